// Round 14
// baseline (462.695 us; speedup 1.0000x reference)
//
#include <hip/hip_runtime.h>

#define E_ 8
#define N_ 4096
#define D_ 1024
#define DFF_ 2048
#define NE_ 65536

typedef __attribute__((ext_vector_type(8))) short short8;
typedef __attribute__((ext_vector_type(4))) float f32x4;
typedef __attribute__((ext_vector_type(16))) float f32x16;

__device__ __forceinline__ unsigned short f2bf(float f) {
  unsigned u = __float_as_uint(f);
  u += 0x7fffu + ((u >> 16) & 1u);   // round-to-nearest-even
  return (unsigned short)(u >> 16);
}
__device__ __forceinline__ float bf2f(unsigned short h) {
  return __uint_as_float(((unsigned)h) << 16);
}

// ---------------- conversion kernels ----------------

__global__ __launch_bounds__(256) void cvt_f32_bf16_vec(
    const float* __restrict__ in, unsigned short* __restrict__ out, int n4) {
  int i = blockIdx.x * 256 + threadIdx.x;
  if (i >= n4) return;
  float4 v = ((const float4*)in)[i];
  ushort4 o;
  o.x = f2bf(v.x); o.y = f2bf(v.y); o.z = f2bf(v.z); o.w = f2bf(v.w);
  ((ushort4*)out)[i] = o;
}

// in: [E][R][C] f32  ->  out: [E][C][R] bf16 (64x64 tiles, float4/ushort4)
__global__ __launch_bounds__(256) void transpose_cvt(
    const float* __restrict__ in, unsigned short* __restrict__ out, int R, int C) {
  __shared__ float tile[64][65];
  const int e = blockIdx.z;
  const float* ine = in + (size_t)e * R * C;
  unsigned short* oute = out + (size_t)e * R * C;
  const int c0 = blockIdx.x * 64, r0 = blockIdx.y * 64;
  const int tx = threadIdx.x & 15, ty = threadIdx.x >> 4;  // 16 x 16
#pragma unroll
  for (int i = 0; i < 4; ++i) {
    float4 v = *(const float4*)(ine + (size_t)(r0 + ty + 16 * i) * C + c0 + tx * 4);
    tile[ty + 16 * i][tx * 4 + 0] = v.x;
    tile[ty + 16 * i][tx * 4 + 1] = v.y;
    tile[ty + 16 * i][tx * 4 + 2] = v.z;
    tile[ty + 16 * i][tx * 4 + 3] = v.w;
  }
  __syncthreads();
#pragma unroll
  for (int i = 0; i < 4; ++i) {
    const int cc = ty + 16 * i;
    const int rr = tx * 4;
    ushort4 o;
    o.x = f2bf(tile[rr + 0][cc]);
    o.y = f2bf(tile[rr + 1][cc]);
    o.z = f2bf(tile[rr + 2][cc]);
    o.w = f2bf(tile[rr + 3][cc]);
    *(ushort4*)(oute + (size_t)(c0 + cc) * R + r0 + rr) = o;
  }
}

// ---------------- CSR build ----------------

__global__ __launch_bounds__(256) void hist_dst(
    const int* __restrict__ ei, int* __restrict__ cnt, int ne) {
  int i = blockIdx.x * 256 + threadIdx.x;
  if (i < ne) atomicAdd(&cnt[ei[ne + i]], 1);
}

__global__ __launch_bounds__(1024) void scan4096(
    const int* __restrict__ cnt, int* __restrict__ rowptr, int* __restrict__ cursor) {
  __shared__ int tmp[1024];
  const int tid = threadIdx.x;
  const int b = tid * 4;
  int c0 = cnt[b + 0], c1 = cnt[b + 1], c2 = cnt[b + 2], c3 = cnt[b + 3];
  int tot = c0 + c1 + c2 + c3;
  tmp[tid] = tot;
  __syncthreads();
  int val = tot;
  for (int off = 1; off < 1024; off <<= 1) {
    int v = 0;
    if (tid >= off) v = tmp[tid - off];
    __syncthreads();
    val += v;
    tmp[tid] = val;
    __syncthreads();
  }
  const int excl = val - tot;
  rowptr[b + 0] = excl;
  rowptr[b + 1] = excl + c0;
  rowptr[b + 2] = excl + c0 + c1;
  rowptr[b + 3] = excl + c0 + c1 + c2;
  cursor[b + 0] = excl;
  cursor[b + 1] = excl + c0;
  cursor[b + 2] = excl + c0 + c1;
  cursor[b + 3] = excl + c0 + c1 + c2;
  if (tid == 1023) rowptr[N_] = val;
}

__global__ __launch_bounds__(256) void fill_csr(
    const int* __restrict__ ei, int* __restrict__ cursor, int* __restrict__ csr, int ne) {
  int i = blockIdx.x * 256 + threadIdx.x;
  if (i < ne) {
    int s = ei[i];
    int d = ei[ne + i];
    int pos = atomicAdd(&cursor[d], 1);
    csr[pos] = s;
  }
}

// ---------------- 256x256 bf16 MFMA GEMM (32x32x16), R9 pipeline ------------
// Identical staging/pipeline to R9 (best measured). Shape swap 16x16x32 ->
// 32x32x16: same frag bytes per tile (A 8 b128, B 4 b128), half the MFMA
// instructions, denser matrix pipe (2382 vs 2075 TF ceiling).
// Per-wave out 128x64 = 4 m-tiles x 2 n-tiles of 32x32; acc f32x16[4][2].
// A operand (32x16/step): lane holds row (l&31), kchunk (l>>5) -> global
// chunk c = ks*2 + (l>>5). Addressing in the paired-row swizzled layout:
// +2048 B per m-tile (32 rows = 16 LDS-rows, slot invariant); ks flips
// slot bit 1 -> byte ^ 32.
// C/D: col = lane&31, row = (reg&3) + 8*(reg>>2) + 4*(lane>>5)  [m74/m101].

#define BAR() asm volatile("s_barrier" ::: "memory")
#define WAIT_VM(n) asm volatile("s_waitcnt vmcnt(" #n ")" ::: "memory")

template <bool RELU>
__global__ __launch_bounds__(512, 1) void gemm256(
    const unsigned short* __restrict__ A, const unsigned short* __restrict__ BT,
    unsigned short* __restrict__ Cb, int M, int Nm, int K, int nbx, int nbxy) {
  __shared__ char lds[131072];

  // XCD-aware swizzle: nwg = nbxy * 8, each XCD gets one expert's blocks
  const int orig = blockIdx.x;
  const int sw = (orig & 7) * nbxy + (orig >> 3);
  const int e = sw / nbxy;
  const int rem = sw - e * nbxy;
  const int by = rem / nbx;
  const int bx = rem - by * nbx;
  const int m0 = by * 256, n0 = bx * 256;

  const int tid = threadIdx.x;
  const int lane = tid & 63;
  const int wid = tid >> 6;
  const int wm = wid >> 2;   // 0..1
  const int wn = wid & 3;    // 0..3
  const int l31 = lane & 31, hi5 = lane >> 5;

  const unsigned short* Ae = A + (size_t)e * M * K + (size_t)m0 * K;
  const unsigned short* Be = BT + (size_t)e * Nm * K + (size_t)n0 * K;
  unsigned short* Ce = Cb + (size_t)e * M * Nm;

  // staging: physical 16B slot p in [0,1024) holds global chunk:
  //   R = p>>3, s = p&7, bc = s ^ (R&7), row = 2R + (bc>>2), kchunk = bc&3
  auto srcoff = [&](int p) -> size_t {
    int R = p >> 3, s = p & 7;
    int bc = s ^ (R & 7);
    int gr = 2 * R + (bc >> 2), c = bc & 3;
    return (size_t)gr * K + (size_t)c * 8;
  };
  const size_t so0 = srcoff(tid);
  const size_t so1 = srcoff(tid + 512);

#define GLD(src_, dst_)                                                        \
  __builtin_amdgcn_global_load_lds(                                            \
      (const __attribute__((address_space(1))) void*)(src_),                   \
      (__attribute__((address_space(3))) void*)(dst_), 16, 0, 0)

  // stage tile t into buffer t&3
#define STAGE(t_)                                                              \
  do {                                                                         \
    char* Lb_ = lds + ((t_) & 3) * 32768;                                      \
    const unsigned short* ga_ = Ae + (size_t)(t_) * 32;                        \
    const unsigned short* gb_ = Be + (size_t)(t_) * 32;                        \
    GLD(ga_ + so0, Lb_ + tid * 16);                                            \
    GLD(ga_ + so1, Lb_ + 8192 + tid * 16);                                     \
    GLD(gb_ + so0, Lb_ + 16384 + tid * 16);                                    \
    GLD(gb_ + so1, Lb_ + 24576 + tid * 16);                                    \
  } while (0)

  // frag base offsets (ks=0, mt/nt=0); +mt*2048, ^ (ks*32)
  const int arow = wm * 128 + l31;
  const int aoff0 = (arow >> 1) * 128 +
                    (((((arow & 1) << 2) | hi5) ^ ((arow >> 1) & 7)) << 4);
  const int brow = wn * 64 + l31;
  const int boff0 = 16384 + (brow >> 1) * 128 +
                    (((((brow & 1) << 2) | hi5) ^ ((brow >> 1) & 7)) << 4);

  f32x16 acc[4][2];
#pragma unroll
  for (int i = 0; i < 4; ++i)
#pragma unroll
    for (int j = 0; j < 2; ++j)
#pragma unroll
      for (int r = 0; r < 16; ++r) acc[i][j][r] = 0.f;

  short8 afA[8], bfA[4], afB[8], bfB[4];  // [mt*2+ks], [nt*2+ks]

  auto dsread = [&](short8* af, short8* bfv, int t) {
    const char* L = lds + (t & 3) * 32768;
#pragma unroll
    for (int mt = 0; mt < 4; ++mt)
#pragma unroll
      for (int ks = 0; ks < 2; ++ks)
        af[mt * 2 + ks] = *(const short8*)(L + ((aoff0 + mt * 2048) ^ (ks * 32)));
#pragma unroll
    for (int nt = 0; nt < 2; ++nt)
#pragma unroll
      for (int ks = 0; ks < 2; ++ks)
        bfv[nt * 2 + ks] = *(const short8*)(L + ((boff0 + nt * 2048) ^ (ks * 32)));
  };
  auto domfma = [&](const short8* af, const short8* bfv) {
    __builtin_amdgcn_s_setprio(1);
#pragma unroll
    for (int mt = 0; mt < 4; ++mt)
#pragma unroll
      for (int nt = 0; nt < 2; ++nt) {
        acc[mt][nt] = __builtin_amdgcn_mfma_f32_32x32x16_bf16(
            af[mt * 2 + 0], bfv[nt * 2 + 0], acc[mt][nt], 0, 0, 0);
        acc[mt][nt] = __builtin_amdgcn_mfma_f32_32x32x16_bf16(
            af[mt * 2 + 1], bfv[nt * 2 + 1], acc[mt][nt], 0, 0, 0);
      }
    __builtin_amdgcn_s_setprio(0);
  };

  const int nkt = K >> 5;  // K/32: 32 (K=1024) or 64 (K=2048); nkt-2 even

  // prologue: stage tiles 0,1,2; read tile-0 frags
  STAGE(0);
  STAGE(1);
  STAGE(2);
  WAIT_VM(8);  // STAGE(0) landed
  BAR();
  dsread(afA, bfA, 0);

  // steady pairs: iterations t and t+1 of {wait;bar;read(t+1);stage(t+3);mfma(t)}
  int t = 0;
  for (; t + 1 < nkt - 2; t += 2) {
    WAIT_VM(4);  // STAGE(t+1) landed (only STAGE(t+2) may remain in flight)
    BAR();       // publish across waves
    dsread(afB, bfB, t + 1);
    if (t + 3 < nkt) STAGE(t + 3);
    domfma(afA, bfA);

    WAIT_VM(4);
    BAR();
    dsread(afA, bfA, t + 2);
    if (t + 4 < nkt) STAGE(t + 4);
    domfma(afB, bfB);
  }
  // t == nkt-2: last staged tile is nkt-1; drain fully, read it, finish
  WAIT_VM(0);
  BAR();
  dsread(afB, bfB, nkt - 1);
  domfma(afA, bfA);
  domfma(afB, bfB);

  // epilogue: C/D col = lane&31, row = (reg&3) + 8*(reg>>2) + 4*(lane>>5)
  const int rowb = m0 + wm * 128 + 4 * hi5;
  const int colb = n0 + wn * 64 + l31;
#pragma unroll
  for (int mt = 0; mt < 4; ++mt)
#pragma unroll
    for (int nt = 0; nt < 2; ++nt)
#pragma unroll
      for (int r = 0; r < 16; ++r) {
        float v = acc[mt][nt][r];
        if (RELU) v = fmaxf(v, 0.f);
        const int row = rowb + mt * 32 + (r & 3) + 8 * (r >> 2);
        Ce[(size_t)row * Nm + colb + nt * 32] = f2bf(v);
      }
#undef STAGE
#undef GLD
}

// ---------------- gather: out[e,dst,:] = sum over in-edges of y[e,src,:] ------
// Column-halved for XCD-L2 residency (R9, -44us) + unroll-4 (R12, -4us).

__global__ __launch_bounds__(128) void gather_sum(
    const unsigned short* __restrict__ y, const int* __restrict__ rowptr,
    const int* __restrict__ csr, float* __restrict__ out) {
  const int orig = blockIdx.x;
  const int sw = (orig & 7) * (E_ * N_ * 2 / 8) + (orig >> 3);
  const int e = sw >> 13;            // / 8192
  const int half = (sw >> 12) & 1;   // column half
  const int dst = sw & 4095;
  const unsigned short* ye = y + (size_t)e * N_ * D_ + half * (D_ / 2);
  float* oute = out + (size_t)e * N_ * D_ + (size_t)dst * D_ + half * (D_ / 2);
  const int t = threadIdx.x;  // 128 threads x 4 elems = 512 = D/2
  const int beg = rowptr[dst], end = rowptr[dst + 1];
  float a0 = 0.f, a1 = 0.f, a2 = 0.f, a3 = 0.f;
  int i = beg;
  for (; i + 3 < end; i += 4) {
    const int s0 = csr[i], s1 = csr[i + 1], s2 = csr[i + 2], s3 = csr[i + 3];
    ushort4 v0 = ((const ushort4*)(ye + (size_t)s0 * D_))[t];
    ushort4 v1 = ((const ushort4*)(ye + (size_t)s1 * D_))[t];
    ushort4 v2 = ((const ushort4*)(ye + (size_t)s2 * D_))[t];
    ushort4 v3 = ((const ushort4*)(ye + (size_t)s3 * D_))[t];
    a0 += (bf2f(v0.x) + bf2f(v1.x)) + (bf2f(v2.x) + bf2f(v3.x));
    a1 += (bf2f(v0.y) + bf2f(v1.y)) + (bf2f(v2.y) + bf2f(v3.y));
    a2 += (bf2f(v0.z) + bf2f(v1.z)) + (bf2f(v2.z) + bf2f(v3.z));
    a3 += (bf2f(v0.w) + bf2f(v1.w)) + (bf2f(v2.w) + bf2f(v3.w));
  }
  for (; i < end; ++i) {
    const int s = csr[i];
    ushort4 v = ((const ushort4*)(ye + (size_t)s * D_))[t];
    a0 += bf2f(v.x); a1 += bf2f(v.y); a2 += bf2f(v.z); a3 += bf2f(v.w);
  }
  f32x4 o = (f32x4){a0, a1, a2, a3};
  __builtin_nontemporal_store(o, (f32x4*)oute + t);
}

// ---------------- launch ----------------

extern "C" void kernel_launch(void* const* d_in, const int* in_sizes, int n_in,
                              void* d_out, int out_size, void* d_ws, size_t ws_size,
                              hipStream_t stream) {
  (void)in_sizes; (void)n_in; (void)out_size; (void)ws_size;
  const float* x = (const float*)d_in[0];
  const float* W1 = (const float*)d_in[1];
  const float* W2 = (const float*)d_in[2];
  const int* ei = (const int*)d_in[3];
  float* out = (float*)d_out;

  char* p = (char*)d_ws;
  auto alloc = [&](size_t b) {
    char* r = p;
    p += (b + 255) & ~(size_t)255;
    return r;
  };
  unsigned short* xbf = (unsigned short*)alloc((size_t)E_ * N_ * D_ * 2);    // 64 MiB
  unsigned short* w1t = (unsigned short*)alloc((size_t)E_ * D_ * DFF_ * 2);  // 32 MiB
  unsigned short* w2t = (unsigned short*)alloc((size_t)E_ * DFF_ * D_ * 2);  // 32 MiB
  unsigned short* h = (unsigned short*)alloc((size_t)E_ * N_ * DFF_ * 2);    // 128 MiB
  unsigned short* y = (unsigned short*)alloc((size_t)E_ * N_ * D_ * 2);      // 64 MiB
  int* cnt = (int*)alloc((size_t)N_ * 4);
  int* rowptr = (int*)alloc((size_t)(N_ + 1) * 4);
  int* cursor = (int*)alloc((size_t)N_ * 4);
  int* csr = (int*)alloc((size_t)NE_ * 4);

  // input conversion
  cvt_f32_bf16_vec<<<(E_ * N_ * D_ / 4 + 255) / 256, 256, 0, stream>>>(x, xbf, E_ * N_ * D_ / 4);
  transpose_cvt<<<dim3(DFF_ / 64, D_ / 64, E_), 256, 0, stream>>>(W1, w1t, D_, DFF_);
  transpose_cvt<<<dim3(D_ / 64, DFF_ / 64, E_), 256, 0, stream>>>(W2, w2t, DFF_, D_);

  // CSR build (edge graph shared across experts)
  hipMemsetAsync(cnt, 0, (size_t)N_ * 4, stream);
  hist_dst<<<NE_ / 256, 256, 0, stream>>>(ei, cnt, NE_);
  scan4096<<<1, 1024, 0, stream>>>(cnt, rowptr, cursor);
  fill_csr<<<NE_ / 256, 256, 0, stream>>>(ei, cursor, csr, NE_);

  // h = relu(x @ W1)   [E][N][DFF] bf16
  {
    int nbx = DFF_ / 256, nby = N_ / 256;
    gemm256<true><<<nbx * nby * E_, 512, 0, stream>>>(xbf, w1t, h, N_, DFF_, D_, nbx, nbx * nby);
  }
  // y = h @ W2         [E][N][D] bf16
  {
    int nbx = D_ / 256, nby = N_ / 256;
    gemm256<false><<<nbx * nby * E_, 512, 0, stream>>>(h, w2t, y, N_, D_, DFF_, nbx, nbx * nby);
  }

  // out = A @ y  (CSR gather, f32 accumulate, L2-resident column halves)
  gather_sum<<<E_ * N_ * 2, 128, 0, stream>>>(y, rowptr, csr, out);
}

// Round 16
// 438.304 us; speedup vs baseline: 1.0556x; 1.0556x over previous
//
#include <hip/hip_runtime.h>

#define E_ 8
#define N_ 4096
#define D_ 1024
#define DFF_ 2048
#define NE_ 65536

typedef __attribute__((ext_vector_type(8))) short short8;
typedef __attribute__((ext_vector_type(4))) float f32x4;

__device__ __forceinline__ unsigned short f2bf(float f) {
  unsigned u = __float_as_uint(f);
  u += 0x7fffu + ((u >> 16) & 1u);   // round-to-nearest-even
  return (unsigned short)(u >> 16);
}
__device__ __forceinline__ float bf2f(unsigned short h) {
  return __uint_as_float(((unsigned)h) << 16);
}

// ---------------- conversion kernels ----------------

__global__ __launch_bounds__(256) void cvt_f32_bf16_vec(
    const float* __restrict__ in, unsigned short* __restrict__ out, int n4) {
  int i = blockIdx.x * 256 + threadIdx.x;
  if (i >= n4) return;
  float4 v = ((const float4*)in)[i];
  ushort4 o;
  o.x = f2bf(v.x); o.y = f2bf(v.y); o.z = f2bf(v.z); o.w = f2bf(v.w);
  ((ushort4*)out)[i] = o;
}

// in: [E][R][C] f32  ->  out: [E][C][R] bf16 (64x64 tiles, float4/ushort4)
__global__ __launch_bounds__(256) void transpose_cvt(
    const float* __restrict__ in, unsigned short* __restrict__ out, int R, int C) {
  __shared__ float tile[64][65];
  const int e = blockIdx.z;
  const float* ine = in + (size_t)e * R * C;
  unsigned short* oute = out + (size_t)e * R * C;
  const int c0 = blockIdx.x * 64, r0 = blockIdx.y * 64;
  const int tx = threadIdx.x & 15, ty = threadIdx.x >> 4;  // 16 x 16
#pragma unroll
  for (int i = 0; i < 4; ++i) {
    float4 v = *(const float4*)(ine + (size_t)(r0 + ty + 16 * i) * C + c0 + tx * 4);
    tile[ty + 16 * i][tx * 4 + 0] = v.x;
    tile[ty + 16 * i][tx * 4 + 1] = v.y;
    tile[ty + 16 * i][tx * 4 + 2] = v.z;
    tile[ty + 16 * i][tx * 4 + 3] = v.w;
  }
  __syncthreads();
#pragma unroll
  for (int i = 0; i < 4; ++i) {
    const int cc = ty + 16 * i;
    const int rr = tx * 4;
    ushort4 o;
    o.x = f2bf(tile[rr + 0][cc]);
    o.y = f2bf(tile[rr + 1][cc]);
    o.z = f2bf(tile[rr + 2][cc]);
    o.w = f2bf(tile[rr + 3][cc]);
    *(ushort4*)(oute + (size_t)(c0 + cc) * R + r0 + rr) = o;
  }
}

// ---------------- CSR build ----------------

__global__ __launch_bounds__(256) void hist_dst(
    const int* __restrict__ ei, int* __restrict__ cnt, int ne) {
  int i = blockIdx.x * 256 + threadIdx.x;
  if (i < ne) atomicAdd(&cnt[ei[ne + i]], 1);
}

__global__ __launch_bounds__(1024) void scan4096(
    const int* __restrict__ cnt, int* __restrict__ rowptr, int* __restrict__ cursor) {
  __shared__ int tmp[1024];
  const int tid = threadIdx.x;
  const int b = tid * 4;
  int c0 = cnt[b + 0], c1 = cnt[b + 1], c2 = cnt[b + 2], c3 = cnt[b + 3];
  int tot = c0 + c1 + c2 + c3;
  tmp[tid] = tot;
  __syncthreads();
  int val = tot;
  for (int off = 1; off < 1024; off <<= 1) {
    int v = 0;
    if (tid >= off) v = tmp[tid - off];
    __syncthreads();
    val += v;
    tmp[tid] = val;
    __syncthreads();
  }
  const int excl = val - tot;
  rowptr[b + 0] = excl;
  rowptr[b + 1] = excl + c0;
  rowptr[b + 2] = excl + c0 + c1;
  rowptr[b + 3] = excl + c0 + c1 + c2;
  cursor[b + 0] = excl;
  cursor[b + 1] = excl + c0;
  cursor[b + 2] = excl + c0 + c1;
  cursor[b + 3] = excl + c0 + c1 + c2;
  if (tid == 1023) rowptr[N_] = val;
}

__global__ __launch_bounds__(256) void fill_csr(
    const int* __restrict__ ei, int* __restrict__ cursor, int* __restrict__ csr, int ne) {
  int i = blockIdx.x * 256 + threadIdx.x;
  if (i < ne) {
    int s = ei[i];
    int d = ei[ne + i];
    int pos = atomicAdd(&cursor[d], 1);
    csr[pos] = s;
  }
}

// ---------------- 256x256 bf16 MFMA GEMM (16x16x32), R9 pipeline -------------
// Best measured config (R9/R12/R13: ~152 us/GEMM, MfmaUtil 40%, 0 conflicts).
// Ceiling evidence: 8-phase x2 (R2/R6 worse), BK=32 circular (R4/R5 equal),
// 128^2 3-blk (R7 worse), 2-blk 256^2 (R11 register-impossible), 32x32x16
// (R14: 1.26e7 bank conflicts, -6%). ~905 TF = plain-HIP simple-structure
// ceiling; past it requires hand-asm-class scheduling (hipBLASLt/HK).

#define BAR() asm volatile("s_barrier" ::: "memory")
#define WAIT_VM(n) asm volatile("s_waitcnt vmcnt(" #n ")" ::: "memory")

template <bool RELU>
__global__ __launch_bounds__(512, 1) void gemm256(
    const unsigned short* __restrict__ A, const unsigned short* __restrict__ BT,
    unsigned short* __restrict__ Cb, int M, int Nm, int K, int nbx, int nbxy) {
  __shared__ char lds[131072];

  // XCD-aware swizzle: nwg = nbxy * 8, each XCD gets one expert's blocks
  const int orig = blockIdx.x;
  const int sw = (orig & 7) * nbxy + (orig >> 3);
  const int e = sw / nbxy;
  const int rem = sw - e * nbxy;
  const int by = rem / nbx;
  const int bx = rem - by * nbx;
  const int m0 = by * 256, n0 = bx * 256;

  const int tid = threadIdx.x;
  const int lane = tid & 63;
  const int wid = tid >> 6;
  const int wm = wid >> 2;   // 0..1
  const int wn = wid & 3;    // 0..3
  const int lo = lane & 15, hi = lane >> 4;

  const unsigned short* Ae = A + (size_t)e * M * K + (size_t)m0 * K;
  const unsigned short* Be = BT + (size_t)e * Nm * K + (size_t)n0 * K;
  unsigned short* Ce = Cb + (size_t)e * M * Nm;

  // staging: physical 16B slot p in [0,1024) holds global chunk:
  //   R = p>>3, s = p&7, bc = s ^ (R&7), row = 2R + (bc>>2), kchunk = bc&3
  auto srcoff = [&](int p) -> size_t {
    int R = p >> 3, s = p & 7;
    int bc = s ^ (R & 7);
    int gr = 2 * R + (bc >> 2), c = bc & 3;
    return (size_t)gr * K + (size_t)c * 8;
  };
  const size_t so0 = srcoff(tid);
  const size_t so1 = srcoff(tid + 512);

#define GLD(src_, dst_)                                                        \
  __builtin_amdgcn_global_load_lds(                                            \
      (const __attribute__((address_space(1))) void*)(src_),                   \
      (__attribute__((address_space(3))) void*)(dst_), 16, 0, 0)

  // stage tile t into buffer t&3
#define STAGE(t_)                                                              \
  do {                                                                         \
    char* Lb_ = lds + ((t_) & 3) * 32768;                                      \
    const unsigned short* ga_ = Ae + (size_t)(t_) * 32;                        \
    const unsigned short* gb_ = Be + (size_t)(t_) * 32;                        \
    GLD(ga_ + so0, Lb_ + tid * 16);                                            \
    GLD(ga_ + so1, Lb_ + 8192 + tid * 16);                                     \
    GLD(gb_ + so0, Lb_ + 16384 + tid * 16);                                    \
    GLD(gb_ + so1, Lb_ + 24576 + tid * 16);                                    \
  } while (0)

  // fragment read offsets (frag fm at +fm*1024; slot invariant across fm
  // since fm*16 rows = fm*8 LDS-rows == 0 mod 8)
  const int slot = (((lo & 1) << 2) | hi) ^ ((lo >> 1) & 7);
  const int aoff = (wm * 64 + (lo >> 1)) * 128 + slot * 16;
  const int boff = 16384 + (wn * 32 + (lo >> 1)) * 128 + slot * 16;

  f32x4 acc[8][4];
#pragma unroll
  for (int i = 0; i < 8; ++i)
#pragma unroll
    for (int j = 0; j < 4; ++j) acc[i][j] = (f32x4){0.f, 0.f, 0.f, 0.f};

  short8 afA[8], bfA[4], afB[8], bfB[4];

  auto dsread = [&](short8* af, short8* bfv, int t) {
    const char* L = lds + (t & 3) * 32768;
#pragma unroll
    for (int fm = 0; fm < 8; ++fm) af[fm] = *(const short8*)(L + aoff + fm * 1024);
#pragma unroll
    for (int fn = 0; fn < 4; ++fn) bfv[fn] = *(const short8*)(L + boff + fn * 1024);
  };
  auto domfma = [&](const short8* af, const short8* bfv) {
    __builtin_amdgcn_s_setprio(1);
#pragma unroll
    for (int fm = 0; fm < 8; ++fm)
#pragma unroll
      for (int fn = 0; fn < 4; ++fn)
        acc[fm][fn] = __builtin_amdgcn_mfma_f32_16x16x32_bf16(af[fm], bfv[fn],
                                                              acc[fm][fn], 0, 0, 0);
    __builtin_amdgcn_s_setprio(0);
  };

  const int nkt = K >> 5;  // K/32: 32 (K=1024) or 64 (K=2048); nkt-2 even

  // prologue: stage tiles 0,1,2; read tile-0 frags
  STAGE(0);
  STAGE(1);
  STAGE(2);
  WAIT_VM(8);  // STAGE(0) landed
  BAR();
  dsread(afA, bfA, 0);

  // steady pairs: iterations t and t+1 of {wait;bar;read(t+1);stage(t+3);mfma(t)}
  int t = 0;
  for (; t + 1 < nkt - 2; t += 2) {
    WAIT_VM(4);  // STAGE(t+1) landed (only STAGE(t+2) may remain in flight)
    BAR();       // publish across waves
    dsread(afB, bfB, t + 1);
    if (t + 3 < nkt) STAGE(t + 3);
    domfma(afA, bfA);

    WAIT_VM(4);
    BAR();
    dsread(afA, bfA, t + 2);
    if (t + 4 < nkt) STAGE(t + 4);
    domfma(afB, bfB);
  }
  // t == nkt-2: last staged tile is nkt-1; drain fully, read it, finish
  WAIT_VM(0);
  BAR();
  dsread(afB, bfB, nkt - 1);
  domfma(afA, bfA);
  domfma(afB, bfB);

  // epilogue: C/D layout col=lane&15, row=(lane>>4)*4+reg
  const int row0 = m0 + wm * 128 + hi * 4;
  const int col0 = n0 + wn * 64 + lo;
#pragma unroll
  for (int fm = 0; fm < 8; ++fm)
#pragma unroll
    for (int fn = 0; fn < 4; ++fn)
#pragma unroll
      for (int r = 0; r < 4; ++r) {
        float v = acc[fm][fn][r];
        if (RELU) v = fmaxf(v, 0.f);
        Ce[(size_t)(row0 + fm * 16 + r) * Nm + (col0 + fn * 16)] = f2bf(v);
      }
#undef STAGE
#undef GLD
}

// ---------------- gather: out[e,dst,:] = sum over in-edges of y[e,src,:] ------
// Column-QUARTERED for XCD-L2 residency: grid [e][quarter][dst], XCD-chunked;
// live y working set = 4096 x 256 cols x 2B = 2 MB (half of one XCD L2,
// headroom for out-stream + csr). 64-thread blocks (1 wave), unroll-4, NT out.

__global__ __launch_bounds__(64) void gather_sum(
    const unsigned short* __restrict__ y, const int* __restrict__ rowptr,
    const int* __restrict__ csr, float* __restrict__ out) {
  const int orig = blockIdx.x;
  const int sw = (orig & 7) * (E_ * N_ * 4 / 8) + (orig >> 3);
  const int e = sw >> 14;            // / 16384
  const int quarter = (sw >> 12) & 3;
  const int dst = sw & 4095;
  const unsigned short* ye = y + (size_t)e * N_ * D_ + quarter * (D_ / 4);
  float* oute = out + (size_t)e * N_ * D_ + (size_t)dst * D_ + quarter * (D_ / 4);
  const int t = threadIdx.x;  // 64 threads x 4 elems = 256 = D/4
  const int beg = rowptr[dst], end = rowptr[dst + 1];
  float a0 = 0.f, a1 = 0.f, a2 = 0.f, a3 = 0.f;
  int i = beg;
  for (; i + 3 < end; i += 4) {
    const int s0 = csr[i], s1 = csr[i + 1], s2 = csr[i + 2], s3 = csr[i + 3];
    ushort4 v0 = ((const ushort4*)(ye + (size_t)s0 * D_))[t];
    ushort4 v1 = ((const ushort4*)(ye + (size_t)s1 * D_))[t];
    ushort4 v2 = ((const ushort4*)(ye + (size_t)s2 * D_))[t];
    ushort4 v3 = ((const ushort4*)(ye + (size_t)s3 * D_))[t];
    a0 += (bf2f(v0.x) + bf2f(v1.x)) + (bf2f(v2.x) + bf2f(v3.x));
    a1 += (bf2f(v0.y) + bf2f(v1.y)) + (bf2f(v2.y) + bf2f(v3.y));
    a2 += (bf2f(v0.z) + bf2f(v1.z)) + (bf2f(v2.z) + bf2f(v3.z));
    a3 += (bf2f(v0.w) + bf2f(v1.w)) + (bf2f(v2.w) + bf2f(v3.w));
  }
  for (; i < end; ++i) {
    const int s = csr[i];
    ushort4 v = ((const ushort4*)(ye + (size_t)s * D_))[t];
    a0 += bf2f(v.x); a1 += bf2f(v.y); a2 += bf2f(v.z); a3 += bf2f(v.w);
  }
  f32x4 o = (f32x4){a0, a1, a2, a3};
  __builtin_nontemporal_store(o, (f32x4*)oute + t);
}

// ---------------- launch ----------------

extern "C" void kernel_launch(void* const* d_in, const int* in_sizes, int n_in,
                              void* d_out, int out_size, void* d_ws, size_t ws_size,
                              hipStream_t stream) {
  (void)in_sizes; (void)n_in; (void)out_size; (void)ws_size;
  const float* x = (const float*)d_in[0];
  const float* W1 = (const float*)d_in[1];
  const float* W2 = (const float*)d_in[2];
  const int* ei = (const int*)d_in[3];
  float* out = (float*)d_out;

  char* p = (char*)d_ws;
  auto alloc = [&](size_t b) {
    char* r = p;
    p += (b + 255) & ~(size_t)255;
    return r;
  };
  unsigned short* xbf = (unsigned short*)alloc((size_t)E_ * N_ * D_ * 2);    // 64 MiB
  unsigned short* w1t = (unsigned short*)alloc((size_t)E_ * D_ * DFF_ * 2);  // 32 MiB
  unsigned short* w2t = (unsigned short*)alloc((size_t)E_ * DFF_ * D_ * 2);  // 32 MiB
  unsigned short* h = (unsigned short*)alloc((size_t)E_ * N_ * DFF_ * 2);    // 128 MiB
  unsigned short* y = (unsigned short*)alloc((size_t)E_ * N_ * D_ * 2);      // 64 MiB
  int* cnt = (int*)alloc((size_t)N_ * 4);
  int* rowptr = (int*)alloc((size_t)(N_ + 1) * 4);
  int* cursor = (int*)alloc((size_t)N_ * 4);
  int* csr = (int*)alloc((size_t)NE_ * 4);

  // input conversion
  cvt_f32_bf16_vec<<<(E_ * N_ * D_ / 4 + 255) / 256, 256, 0, stream>>>(x, xbf, E_ * N_ * D_ / 4);
  transpose_cvt<<<dim3(DFF_ / 64, D_ / 64, E_), 256, 0, stream>>>(W1, w1t, D_, DFF_);
  transpose_cvt<<<dim3(D_ / 64, DFF_ / 64, E_), 256, 0, stream>>>(W2, w2t, DFF_, D_);

  // CSR build (edge graph shared across experts)
  hipMemsetAsync(cnt, 0, (size_t)N_ * 4, stream);
  hist_dst<<<NE_ / 256, 256, 0, stream>>>(ei, cnt, NE_);
  scan4096<<<1, 1024, 0, stream>>>(cnt, rowptr, cursor);
  fill_csr<<<NE_ / 256, 256, 0, stream>>>(ei, cursor, csr, NE_);

  // h = relu(x @ W1)   [E][N][DFF] bf16
  {
    int nbx = DFF_ / 256, nby = N_ / 256;
    gemm256<true><<<nbx * nby * E_, 512, 0, stream>>>(xbf, w1t, h, N_, DFF_, D_, nbx, nbx * nby);
  }
  // y = h @ W2         [E][N][D] bf16
  {
    int nbx = D_ / 256, nby = N_ / 256;
    gemm256<false><<<nbx * nby * E_, 512, 0, stream>>>(h, w2t, y, N_, D_, DFF_, nbx, nbx * nby);
  }

  // out = A @ y  (CSR gather, f32 accumulate, L2-resident column quarters)
  gather_sum<<<E_ * N_ * 4, 64, 0, stream>>>(y, rowptr, csr, out);
}

// Round 17
// 427.412 us; speedup vs baseline: 1.0826x; 1.0255x over previous
//
#include <hip/hip_runtime.h>

#define E_ 8
#define N_ 4096
#define D_ 1024
#define DFF_ 2048
#define NE_ 65536

typedef __attribute__((ext_vector_type(8))) short short8;
typedef __attribute__((ext_vector_type(4))) float f32x4;

__device__ __forceinline__ unsigned short f2bf(float f) {
  unsigned u = __float_as_uint(f);
  u += 0x7fffu + ((u >> 16) & 1u);   // round-to-nearest-even
  return (unsigned short)(u >> 16);
}
__device__ __forceinline__ float bf2f(unsigned short h) {
  return __uint_as_float(((unsigned)h) << 16);
}

// ---------------- conversion kernels ----------------

__global__ __launch_bounds__(256) void cvt_f32_bf16_vec(
    const float* __restrict__ in, unsigned short* __restrict__ out, int n4) {
  int i = blockIdx.x * 256 + threadIdx.x;
  if (i >= n4) return;
  float4 v = ((const float4*)in)[i];
  ushort4 o;
  o.x = f2bf(v.x); o.y = f2bf(v.y); o.z = f2bf(v.z); o.w = f2bf(v.w);
  ((ushort4*)out)[i] = o;
}

// in: [E][R][C] f32  ->  out: [E][C][R] bf16 (64x64 tiles, float4/ushort4)
__global__ __launch_bounds__(256) void transpose_cvt(
    const float* __restrict__ in, unsigned short* __restrict__ out, int R, int C) {
  __shared__ float tile[64][65];
  const int e = blockIdx.z;
  const float* ine = in + (size_t)e * R * C;
  unsigned short* oute = out + (size_t)e * R * C;
  const int c0 = blockIdx.x * 64, r0 = blockIdx.y * 64;
  const int tx = threadIdx.x & 15, ty = threadIdx.x >> 4;  // 16 x 16
#pragma unroll
  for (int i = 0; i < 4; ++i) {
    float4 v = *(const float4*)(ine + (size_t)(r0 + ty + 16 * i) * C + c0 + tx * 4);
    tile[ty + 16 * i][tx * 4 + 0] = v.x;
    tile[ty + 16 * i][tx * 4 + 1] = v.y;
    tile[ty + 16 * i][tx * 4 + 2] = v.z;
    tile[ty + 16 * i][tx * 4 + 3] = v.w;
  }
  __syncthreads();
#pragma unroll
  for (int i = 0; i < 4; ++i) {
    const int cc = ty + 16 * i;
    const int rr = tx * 4;
    ushort4 o;
    o.x = f2bf(tile[rr + 0][cc]);
    o.y = f2bf(tile[rr + 1][cc]);
    o.z = f2bf(tile[rr + 2][cc]);
    o.w = f2bf(tile[rr + 3][cc]);
    *(ushort4*)(oute + (size_t)(c0 + cc) * R + r0 + rr) = o;
  }
}

// ---------------- CSR build ----------------

__global__ __launch_bounds__(256) void hist_dst(
    const int* __restrict__ ei, int* __restrict__ cnt, int ne) {
  int i = blockIdx.x * 256 + threadIdx.x;
  if (i < ne) atomicAdd(&cnt[ei[ne + i]], 1);
}

__global__ __launch_bounds__(1024) void scan4096(
    const int* __restrict__ cnt, int* __restrict__ rowptr, int* __restrict__ cursor) {
  __shared__ int tmp[1024];
  const int tid = threadIdx.x;
  const int b = tid * 4;
  int c0 = cnt[b + 0], c1 = cnt[b + 1], c2 = cnt[b + 2], c3 = cnt[b + 3];
  int tot = c0 + c1 + c2 + c3;
  tmp[tid] = tot;
  __syncthreads();
  int val = tot;
  for (int off = 1; off < 1024; off <<= 1) {
    int v = 0;
    if (tid >= off) v = tmp[tid - off];
    __syncthreads();
    val += v;
    tmp[tid] = val;
    __syncthreads();
  }
  const int excl = val - tot;
  rowptr[b + 0] = excl;
  rowptr[b + 1] = excl + c0;
  rowptr[b + 2] = excl + c0 + c1;
  rowptr[b + 3] = excl + c0 + c1 + c2;
  cursor[b + 0] = excl;
  cursor[b + 1] = excl + c0;
  cursor[b + 2] = excl + c0 + c1;
  cursor[b + 3] = excl + c0 + c1 + c2;
  if (tid == 1023) rowptr[N_] = val;
}

__global__ __launch_bounds__(256) void fill_csr(
    const int* __restrict__ ei, int* __restrict__ cursor, int* __restrict__ csr, int ne) {
  int i = blockIdx.x * 256 + threadIdx.x;
  if (i < ne) {
    int s = ei[i];
    int d = ei[ne + i];
    int pos = atomicAdd(&cursor[d], 1);
    csr[pos] = s;
  }
}

// ---------------- 256x256 bf16 MFMA GEMM (16x16x32), R9 pipeline -------------
// Best measured config (R9/R12/R13/R16: ~151 us/GEMM, MfmaUtil 40%, 0
// conflicts). Ceiling evidence: 8-phase x2 (R2/R6 worse), BK=32 circular
// (R4/R5 equal), 128^2 3-blk (R7 worse), 2-blk 256^2 (R11 register-
// impossible), 32x32x16 (R14: 1.26e7 bank conflicts, -6%). ~905 TF = the
// plain-HIP simple-structure ceiling on this part.

#define BAR() asm volatile("s_barrier" ::: "memory")
#define WAIT_VM(n) asm volatile("s_waitcnt vmcnt(" #n ")" ::: "memory")

template <bool RELU>
__global__ __launch_bounds__(512, 1) void gemm256(
    const unsigned short* __restrict__ A, const unsigned short* __restrict__ BT,
    unsigned short* __restrict__ Cb, int M, int Nm, int K, int nbx, int nbxy) {
  __shared__ char lds[131072];

  // XCD-aware swizzle: nwg = nbxy * 8, each XCD gets one expert's blocks
  const int orig = blockIdx.x;
  const int sw = (orig & 7) * nbxy + (orig >> 3);
  const int e = sw / nbxy;
  const int rem = sw - e * nbxy;
  const int by = rem / nbx;
  const int bx = rem - by * nbx;
  const int m0 = by * 256, n0 = bx * 256;

  const int tid = threadIdx.x;
  const int lane = tid & 63;
  const int wid = tid >> 6;
  const int wm = wid >> 2;   // 0..1
  const int wn = wid & 3;    // 0..3
  const int lo = lane & 15, hi = lane >> 4;

  const unsigned short* Ae = A + (size_t)e * M * K + (size_t)m0 * K;
  const unsigned short* Be = BT + (size_t)e * Nm * K + (size_t)n0 * K;
  unsigned short* Ce = Cb + (size_t)e * M * Nm;

  // staging: physical 16B slot p in [0,1024) holds global chunk:
  //   R = p>>3, s = p&7, bc = s ^ (R&7), row = 2R + (bc>>2), kchunk = bc&3
  auto srcoff = [&](int p) -> size_t {
    int R = p >> 3, s = p & 7;
    int bc = s ^ (R & 7);
    int gr = 2 * R + (bc >> 2), c = bc & 3;
    return (size_t)gr * K + (size_t)c * 8;
  };
  const size_t so0 = srcoff(tid);
  const size_t so1 = srcoff(tid + 512);

#define GLD(src_, dst_)                                                        \
  __builtin_amdgcn_global_load_lds(                                            \
      (const __attribute__((address_space(1))) void*)(src_),                   \
      (__attribute__((address_space(3))) void*)(dst_), 16, 0, 0)

  // stage tile t into buffer t&3
#define STAGE(t_)                                                              \
  do {                                                                         \
    char* Lb_ = lds + ((t_) & 3) * 32768;                                      \
    const unsigned short* ga_ = Ae + (size_t)(t_) * 32;                        \
    const unsigned short* gb_ = Be + (size_t)(t_) * 32;                        \
    GLD(ga_ + so0, Lb_ + tid * 16);                                            \
    GLD(ga_ + so1, Lb_ + 8192 + tid * 16);                                     \
    GLD(gb_ + so0, Lb_ + 16384 + tid * 16);                                    \
    GLD(gb_ + so1, Lb_ + 24576 + tid * 16);                                    \
  } while (0)

  // fragment read offsets (frag fm at +fm*1024; slot invariant across fm
  // since fm*16 rows = fm*8 LDS-rows == 0 mod 8)
  const int slot = (((lo & 1) << 2) | hi) ^ ((lo >> 1) & 7);
  const int aoff = (wm * 64 + (lo >> 1)) * 128 + slot * 16;
  const int boff = 16384 + (wn * 32 + (lo >> 1)) * 128 + slot * 16;

  f32x4 acc[8][4];
#pragma unroll
  for (int i = 0; i < 8; ++i)
#pragma unroll
    for (int j = 0; j < 4; ++j) acc[i][j] = (f32x4){0.f, 0.f, 0.f, 0.f};

  short8 afA[8], bfA[4], afB[8], bfB[4];

  auto dsread = [&](short8* af, short8* bfv, int t) {
    const char* L = lds + (t & 3) * 32768;
#pragma unroll
    for (int fm = 0; fm < 8; ++fm) af[fm] = *(const short8*)(L + aoff + fm * 1024);
#pragma unroll
    for (int fn = 0; fn < 4; ++fn) bfv[fn] = *(const short8*)(L + boff + fn * 1024);
  };
  auto domfma = [&](const short8* af, const short8* bfv) {
    __builtin_amdgcn_s_setprio(1);
#pragma unroll
    for (int fm = 0; fm < 8; ++fm)
#pragma unroll
      for (int fn = 0; fn < 4; ++fn)
        acc[fm][fn] = __builtin_amdgcn_mfma_f32_16x16x32_bf16(af[fm], bfv[fn],
                                                              acc[fm][fn], 0, 0, 0);
    __builtin_amdgcn_s_setprio(0);
  };

  const int nkt = K >> 5;  // K/32: 32 (K=1024) or 64 (K=2048); nkt-2 even

  // prologue: stage tiles 0,1,2; read tile-0 frags
  STAGE(0);
  STAGE(1);
  STAGE(2);
  WAIT_VM(8);  // STAGE(0) landed
  BAR();
  dsread(afA, bfA, 0);

  // steady pairs: iterations t and t+1 of {wait;bar;read(t+1);stage(t+3);mfma(t)}
  int t = 0;
  for (; t + 1 < nkt - 2; t += 2) {
    WAIT_VM(4);  // STAGE(t+1) landed (only STAGE(t+2) may remain in flight)
    BAR();       // publish across waves
    dsread(afB, bfB, t + 1);
    if (t + 3 < nkt) STAGE(t + 3);
    domfma(afA, bfA);

    WAIT_VM(4);
    BAR();
    dsread(afA, bfA, t + 2);
    if (t + 4 < nkt) STAGE(t + 4);
    domfma(afB, bfB);
  }
  // t == nkt-2: last staged tile is nkt-1; drain fully, read it, finish
  WAIT_VM(0);
  BAR();
  dsread(afB, bfB, nkt - 1);
  domfma(afA, bfA);
  domfma(afB, bfB);

  // epilogue: C/D layout col=lane&15, row=(lane>>4)*4+reg
  const int row0 = m0 + wm * 128 + hi * 4;
  const int col0 = n0 + wn * 64 + lo;
#pragma unroll
  for (int fm = 0; fm < 8; ++fm)
#pragma unroll
    for (int fn = 0; fn < 4; ++fn)
#pragma unroll
      for (int r = 0; r < 4; ++r) {
        float v = acc[fm][fn][r];
        if (RELU) v = fmaxf(v, 0.f);
        Ce[(size_t)(row0 + fm * 16 + r) * Nm + (col0 + fn * 16)] = f2bf(v);
      }
#undef STAGE
#undef GLD
}

// ---------------- gather: out[e,dst,:] = sum over in-edges of y[e,src,:] ------
// Column-halved (4 MB/XCD working set, R9-proven) with 16 B/lane loads:
// 64 threads x short8 = 1024 B = one row-half per wave-load (coalescing sweet
// spot, half the load instructions of ushort4). Unroll-4 MLP + NT stores.

__global__ __launch_bounds__(64) void gather_sum(
    const unsigned short* __restrict__ y, const int* __restrict__ rowptr,
    const int* __restrict__ csr, float* __restrict__ out) {
  const int orig = blockIdx.x;
  const int sw = (orig & 7) * (E_ * N_ * 2 / 8) + (orig >> 3);
  const int e = sw >> 13;            // / 8192
  const int half = (sw >> 12) & 1;   // column half
  const int dst = sw & 4095;
  const unsigned short* ye = y + (size_t)e * N_ * D_ + half * (D_ / 2);
  float* oute = out + (size_t)e * N_ * D_ + (size_t)dst * D_ + half * (D_ / 2);
  const int t = threadIdx.x;  // 64 threads x 8 elems = 512 = D/2
  const int beg = rowptr[dst], end = rowptr[dst + 1];
  float a[8];
#pragma unroll
  for (int j = 0; j < 8; ++j) a[j] = 0.f;
  int i = beg;
  for (; i + 3 < end; i += 4) {
    const int s0 = csr[i], s1 = csr[i + 1], s2 = csr[i + 2], s3 = csr[i + 3];
    short8 v0 = ((const short8*)(ye + (size_t)s0 * D_))[t];
    short8 v1 = ((const short8*)(ye + (size_t)s1 * D_))[t];
    short8 v2 = ((const short8*)(ye + (size_t)s2 * D_))[t];
    short8 v3 = ((const short8*)(ye + (size_t)s3 * D_))[t];
#pragma unroll
    for (int j = 0; j < 8; ++j)
      a[j] += (bf2f((unsigned short)v0[j]) + bf2f((unsigned short)v1[j])) +
              (bf2f((unsigned short)v2[j]) + bf2f((unsigned short)v3[j]));
  }
  for (; i < end; ++i) {
    const int s = csr[i];
    short8 v = ((const short8*)(ye + (size_t)s * D_))[t];
#pragma unroll
    for (int j = 0; j < 8; ++j) a[j] += bf2f((unsigned short)v[j]);
  }
  f32x4 o0 = (f32x4){a[0], a[1], a[2], a[3]};
  f32x4 o1 = (f32x4){a[4], a[5], a[6], a[7]};
  __builtin_nontemporal_store(o0, (f32x4*)oute + 2 * t);
  __builtin_nontemporal_store(o1, (f32x4*)oute + 2 * t + 1);
}

// ---------------- launch ----------------

extern "C" void kernel_launch(void* const* d_in, const int* in_sizes, int n_in,
                              void* d_out, int out_size, void* d_ws, size_t ws_size,
                              hipStream_t stream) {
  (void)in_sizes; (void)n_in; (void)out_size; (void)ws_size;
  const float* x = (const float*)d_in[0];
  const float* W1 = (const float*)d_in[1];
  const float* W2 = (const float*)d_in[2];
  const int* ei = (const int*)d_in[3];
  float* out = (float*)d_out;

  char* p = (char*)d_ws;
  auto alloc = [&](size_t b) {
    char* r = p;
    p += (b + 255) & ~(size_t)255;
    return r;
  };
  unsigned short* xbf = (unsigned short*)alloc((size_t)E_ * N_ * D_ * 2);    // 64 MiB
  unsigned short* w1t = (unsigned short*)alloc((size_t)E_ * D_ * DFF_ * 2);  // 32 MiB
  unsigned short* w2t = (unsigned short*)alloc((size_t)E_ * DFF_ * D_ * 2);  // 32 MiB
  unsigned short* h = (unsigned short*)alloc((size_t)E_ * N_ * DFF_ * 2);    // 128 MiB
  unsigned short* y = (unsigned short*)alloc((size_t)E_ * N_ * D_ * 2);      // 64 MiB
  int* cnt = (int*)alloc((size_t)N_ * 4);
  int* rowptr = (int*)alloc((size_t)(N_ + 1) * 4);
  int* cursor = (int*)alloc((size_t)N_ * 4);
  int* csr = (int*)alloc((size_t)NE_ * 4);

  // input conversion
  cvt_f32_bf16_vec<<<(E_ * N_ * D_ / 4 + 255) / 256, 256, 0, stream>>>(x, xbf, E_ * N_ * D_ / 4);
  transpose_cvt<<<dim3(DFF_ / 64, D_ / 64, E_), 256, 0, stream>>>(W1, w1t, D_, DFF_);
  transpose_cvt<<<dim3(D_ / 64, DFF_ / 64, E_), 256, 0, stream>>>(W2, w2t, DFF_, D_);

  // CSR build (edge graph shared across experts)
  hipMemsetAsync(cnt, 0, (size_t)N_ * 4, stream);
  hist_dst<<<NE_ / 256, 256, 0, stream>>>(ei, cnt, NE_);
  scan4096<<<1, 1024, 0, stream>>>(cnt, rowptr, cursor);
  fill_csr<<<NE_ / 256, 256, 0, stream>>>(ei, cursor, csr, NE_);

  // h = relu(x @ W1)   [E][N][DFF] bf16
  {
    int nbx = DFF_ / 256, nby = N_ / 256;
    gemm256<true><<<nbx * nby * E_, 512, 0, stream>>>(xbf, w1t, h, N_, DFF_, D_, nbx, nbx * nby);
  }
  // y = h @ W2         [E][N][D] bf16
  {
    int nbx = D_ / 256, nby = N_ / 256;
    gemm256<false><<<nbx * nby * E_, 512, 0, stream>>>(h, w2t, y, N_, D_, DFF_, nbx, nbx * nby);
  }

  // out = A @ y  (CSR gather, f32 accumulate, L2-resident column halves)
  gather_sum<<<E_ * N_ * 2, 64, 0, stream>>>(y, rowptr, csr, out);
}